// Round 2
// baseline (745.107 us; speedup 1.0000x reference)
//
#include <hip/hip_runtime.h>

// MeanAggregator: out[b,:] = mean over {neighbours[b,0..9], nodes[b]} of features[idx,:]
// B=100000, K=10, N=1000000, D=128.
//
// v3: L3-tiled two-pass gather. The feature table (512 MB) is exactly 2x the
// 256 MiB Infinity Cache, and round-1 A/B showed the gather is bound by
// random-miss latency x per-CU miss slots (1.9 TB/s effective regardless of
// issue structure). So: warm half the table into the memory-side cache with a
// streaming read, then gather only indices in that half (random reads become
// MALL hits at ~2x lower latency), twice. Out-of-range lanes load a hot dummy
// row and are masked out of the sum, keeping the 11 loads batch-issued and
// non-divergent. Output uses nontemporal ld/st so the 51 MB out stream doesn't
// evict the warmed tile.

#define KNEIGH 10
#define DDIM 128

typedef float v4f __attribute__((ext_vector_type(4)));

// Streaming warm: pull [lo_elem, lo_elem+n_elem) floats of the feature table
// through the memory-side Infinity Cache (allocates on read).
__global__ __launch_bounds__(256) void MeanAggregator_warm_kernel(
    const float* __restrict__ features, long long lo_elem, long long n_elem,
    float* __restrict__ sink)
{
    const long long tid    = (long long)blockIdx.x * 256 + threadIdx.x;
    const long long stride = (long long)gridDim.x * 256;
    const v4f* p = (const v4f*)(features + lo_elem);
    const long long nvec = n_elem >> 2;
    v4f acc = {0.f, 0.f, 0.f, 0.f};
    for (long long i = tid; i < nvec; i += stride) acc += p[i];
    if (acc.x == 1234567.25f && acc.y == -7654321.125f)
        sink[threadIdx.x] = acc.z + acc.w;   // never true; defeats DCE
}

// Gather pass: accumulate neighbours with index in [lo, hi). Two nodes per
// wave (lanes 0-31 node A, 32-63 node B); each lane loads float4 so one
// instruction moves up to 1 KB across two random rows.
__global__ __launch_bounds__(256) void MeanAggregator_36386962932386_kernel(
    const int* __restrict__ nodes,
    const int* __restrict__ neighbours,
    const float* __restrict__ features,
    float* __restrict__ out,
    int B, int lo, int hi, int final_pass)
{
    const int wave = blockIdx.x * 4 + (threadIdx.x >> 6);
    const int lane = threadIdx.x & 63;
    const int half = lane >> 5;              // 0 -> node A, 1 -> node B
    const int hl   = lane & 31;              // lane within half-wave
    const unsigned hb = (unsigned)hl * 16u;  // byte offset within feature row

    const int npairs = (B + 1) >> 1;
    if (wave >= npairs) return;
    const int node = wave * 2 + half;
    const int n = node < B ? node : 0;

    // Indices (int2-vectorized: 10 ints -> 5 x int2, 8B-aligned rows).
    int idx[KNEIGH + 1];
    {
        const int2* p2 = (const int2*)neighbours + n * (KNEIGH / 2);
#pragma unroll
        for (int j = 0; j < KNEIGH / 2; ++j) {
            const int2 t = p2[j];
            idx[2 * j]     = t.x;
            idx[2 * j + 1] = t.y;
        }
        idx[KNEIGH] = nodes[n];
    }

    // Predicated gathers: out-of-range indices read row `lo` (cache-hot),
    // result masked out of the accumulation. Keeps all 11 loads independent
    // and batch-issued with a single vmcnt wait.
    v4f v[KNEIGH + 1];
    bool m[KNEIGH + 1];
#pragma unroll
    for (int j = 0; j <= KNEIGH; ++j) {
        const int ix = idx[j];
        const bool in = (ix >= lo) & (ix < hi);
        const int e = in ? ix : lo;
        m[j] = in;
        v[j] = *(const v4f*)((const char*)features + (unsigned)e * (DDIM * 4) + hb);
    }

    const v4f z = {0.f, 0.f, 0.f, 0.f};
    v4f acc = z;
#pragma unroll
    for (int j = 0; j <= KNEIGH; ++j) acc += (m[j] ? v[j] : z);

    if (node < B) {
        char* op = (char*)out + (unsigned)node * (DDIM * 4) + hb;
        if (final_pass) {
            v4f prev = __builtin_nontemporal_load((const v4f*)op);
            v4f r = (acc + prev) * (1.0f / (KNEIGH + 1));
            __builtin_nontemporal_store(r, (v4f*)op);
        } else {
            __builtin_nontemporal_store(acc, (v4f*)op);
        }
    }
}

extern "C" void kernel_launch(void* const* d_in, const int* in_sizes, int n_in,
                              void* d_out, int out_size, void* d_ws, size_t ws_size,
                              hipStream_t stream)
{
    const int* nodes      = (const int*)d_in[0];
    const int* neighbours = (const int*)d_in[1];
    const float* features = (const float*)d_in[2];
    float* out            = (float*)d_out;

    const int B = in_sizes[0];                       // 100000
    long long featElems = in_sizes[2];               // N * D (element count)
    int N = (int)(featElems / DDIM);
    if (N <= 0) N = 1000000;
    const int H = N / 2;                             // split table into 2 L3-sized tiles

    const int npairs  = (B + 1) / 2;
    const int gblocks = (npairs + 3) / 4;            // one pair per wave, 4 waves/block
    const int wblocks = 2048;                        // streaming warm grid

    float* sink = ws_size ? (float*)d_ws : out;      // DCE-defeat target (never written)

    // Pass 0: warm rows [0, H), gather in-range, store raw partial sums.
    MeanAggregator_warm_kernel<<<wblocks, 256, 0, stream>>>(
        features, 0LL, (long long)H * DDIM, sink);
    MeanAggregator_36386962932386_kernel<<<gblocks, 256, 0, stream>>>(
        nodes, neighbours, features, out, B, 0, H, 0);

    // Pass 1: warm rows [H, N), gather, add partials, scale by 1/11.
    MeanAggregator_warm_kernel<<<wblocks, 256, 0, stream>>>(
        features, (long long)H * DDIM, (long long)(N - H) * DDIM, sink);
    MeanAggregator_36386962932386_kernel<<<gblocks, 256, 0, stream>>>(
        nodes, neighbours, features, out, B, H, N, 1);
}